// Round 16
// baseline (686.526 us; speedup 1.0000x reference)
//
#include <hip/hip_runtime.h>
#include <math.h>

// FusionNeRF round 18:
//   - r17 (deeper pipeline) NULL at VGPR 156 -> latency already hidden; the
//     stall is THROUGHPUT: per kstep/CU: MFMA 155cyc, L2 weights 290cyc,
//     LDS 380-520cyc (4 waves redundantly read the full act tile). Wall 573.
//   - r18: BM=256 -> MFMA/kstep doubles (310cyc) while weight stream stays
//     16KB/kstep => L2 no longer binding; LDS ratio unchanged but amortized.
//     LDS fits by IN-PLACE encoding: E written into Hb rows[0..127] (BAR1
//     alias protocol guarantees read-all-before-write-any), re-encoded before
//     the dynamic MLP (double-angle is cheap). acc[4][16]=256 AGPR at
//     1 wave/SIMD (cap 512). K-step = 4 quarters, r16's validated counted-wait
//     protocol. layer256 noinline (2 bodies, 8 calls) -> ~15KB code.

#define RAYS 2048
#define SAMP 128
#define MTOT (RAYS * SAMP)
#define HD   256
#define BM   256             // samples per block (r18: doubled again)
#define HS   264             // act LDS stride (bf16), 256 (+8 pad)

// output float offsets
#define OUT_RGB   0
#define OUT_DEPTH 6144
#define OUT_W     8192
#define OUT_SW    270336
#define OUT_DW    532480

// bf16 weight workspace offsets (elements)
#define SW0 0
#define SW1 32768
#define SW2 98304
#define SW3 163840
#define SW4 229376
#define DW0 233472
#define DW1 266240
#define DW2 331776
#define DW3 397312
#define DW4 462848
#define WTOT 466944

typedef __attribute__((ext_vector_type(8))) short short8;
typedef __attribute__((ext_vector_type(4))) float f32x4;
typedef __attribute__((ext_vector_type(2))) float f32x2;
typedef __attribute__((ext_vector_type(2))) unsigned int uint2v;

__device__ __forceinline__ float sigm(float x) { return 1.0f / (1.0f + expf(-x)); }

__device__ __forceinline__ short f2bf(float f) {   // RNE fp32 -> bf16
    union { float f; unsigned u; } v; v.f = f;
    unsigned r = v.u + 0x7fffu + ((v.u >> 16) & 1u);
    return (short)(r >> 16);
}

// Unmovable memory ops (volatile asm). Counted waits + sched_barrier(0) (rule #18).
#define GLB_LOAD(dst, ptr, imm) \
    asm volatile("global_load_dwordx4 %0, %1, off offset:%c2" \
                 : "=v"(dst) : "v"(ptr), "n"(imm))
#define LDS_READ(dst, addr, imm) \
    asm volatile("ds_read_b128 %0, %1 offset:%c2" \
                 : "=v"(dst) : "v"(addr), "n"(imm))
#define WAITCNT(vm, lg) do { \
    asm volatile("s_waitcnt vmcnt(%c0) lgkmcnt(%c1)" :: "n"(vm), "n"(lg)); \
    __builtin_amdgcn_sched_barrier(0); } while (0)

// Barrier with LDS drain only (validated r5/r8/r12/r14/r16).
__device__ __forceinline__ void bar_lgkm() {
    __builtin_amdgcn_sched_barrier(0);
    asm volatile("s_waitcnt lgkmcnt(0)\n\ts_barrier" ::: "memory");
    __builtin_amdgcn_sched_barrier(0);
}
// Ordering-only barrier (all reads already drained / consumed by dataflow).
__device__ __forceinline__ void bar_only() {
    __builtin_amdgcn_sched_barrier(0);
    asm volatile("s_barrier" ::: "memory");
    __builtin_amdgcn_sched_barrier(0);
}

// ---------------- weight prep: W[K][N] fp32 -> Wt[Npad][Kpad] bf16 --------------
__device__ __forceinline__ void conv1(const float* __restrict__ src, short* __restrict__ dst,
                                      int local, int K, int N, int Kpad) {
    const int n = local / Kpad, k = local - n * Kpad;
    const float v = (k < K && n < N) ? src[k * N + n] : 0.0f;
    dst[local] = f2bf(v);
}

__global__ __launch_bounds__(256)
void prep_weights(const float* sW0, const float* sW1, const float* sW2,
                  const float* sW3, const float* sW4,
                  const float* dW0, const float* dW1, const float* dW2,
                  const float* dW3, const float* dW4, short* __restrict__ dst)
{
    const int idx = blockIdx.x * 256 + threadIdx.x;
    if (idx >= WTOT) return;
    if      (idx < SW1) conv1(sW0, dst + SW0, idx - SW0,  90, 256, 128);
    else if (idx < SW2) conv1(sW1, dst + SW1, idx - SW1, 256, 256, 256);
    else if (idx < SW3) conv1(sW2, dst + SW2, idx - SW2, 256, 256, 256);
    else if (idx < SW4) conv1(sW3, dst + SW3, idx - SW3, 256, 256, 256);
    else if (idx < DW0) conv1(sW4, dst + SW4, idx - SW4, 256,   4, 256);
    else if (idx < DW1) conv1(dW0, dst + DW0, idx - DW0,  99, 256, 128);
    else if (idx < DW2) conv1(dW1, dst + DW1, idx - DW1, 256, 256, 256);
    else if (idx < DW3) conv1(dW2, dst + DW2, idx - DW2, 256, 256, 256);
    else if (idx < DW4) conv1(dW3, dst + DW3, idx - DW3, 256, 256, 256);
    else                conv1(dW4, dst + DW4, idx - DW4, 256,   5, 256);
}

// ---------------- encoding -> Hb rows[0..127] (stride HS), double-angle ---------
__device__ __attribute__((noinline))
void encode_E(short* __restrict__ Hb, const float* __restrict__ points,
              const float* __restrict__ dirsv, const float* __restrict__ timev,
              int m0, int tid)
{
    for (int idx = tid; idx < 7 * BM; idx += 256) {
        const int c = idx >> 8, s = idx & 255, m = m0 + s;   // c wave-uniform
        short* E = Hb + (size_t)s * HS;
        float x; int dbase, nb, dstep, coff;
        if (c < 3)      { x = points[m * 3 + c];     E[c]      = f2bf(x); dbase = 3 + c;  nb = 10; dstep = 6; coff = 3; }
        else if (c < 6) { x = dirsv[m * 3 + c - 3];  E[60 + c] = f2bf(x); dbase = 63 + c; nb = 4;  dstep = 6; coff = 3; }
        else            { x = timev[m];              E[90]     = f2bf(x); dbase = 91;     nb = 4;  dstep = 2; coff = 1; }
        float sl = sinf(x), cl = cosf(x);
        int d = dbase;
        E[d] = f2bf(sl); E[d + coff] = f2bf(cl);
        for (int l = 1; l < nb; l++) {
            const float s2 = 2.0f * sl * cl;
            const float c2 = cl * cl - sl * sl;
            d += dstep;
            E[d] = f2bf(s2); E[d + coff] = f2bf(c2);
            sl = s2; cl = c2;
        }
    }
    for (int idx = tid; idx < BM * 32; idx += 256) {   // zero pad k=99..127
        const int s = idx >> 5, d = 96 + (idx & 31);
        if (d >= 99) Hb[(size_t)s * HS + d] = 0;
    }
}

// ---------------- MFMA dense layer: 64feat x 256samp per wave, 4-quarter kstep --
// A-operand = weights Wt[256][K] (global, L2-hot), B-operand = acts [256][HS] (LDS,
// may alias O in-place -- BAR1 protocol). Phases P=0..4*KS-1 (kk=P>>2, q=P&3):
// q0 issues W(kk+1) [retired at next kk's q0 via vm=4]; every phase issues
// A(P+1) [retired next phase via lgkm=4]. Last phase waits (0,0): self-contained.
template <int KSTEPS, bool RELU>
__device__ __attribute__((noinline))
void layer256(const short* A, const short* __restrict__ Wt,
              const float* __restrict__ bias, short* O, int tid)
{
    const int w = tid >> 6, lane = tid & 63, qq = lane >> 4, col = lane & 15;
    constexpr int K = KSTEPS * 32;
    constexpr int NPH = 4 * KSTEPS;

    const short* wp0 = Wt + (size_t)(w * 64 +  0 + col) * K + qq * 8;
    const short* wp1 = Wt + (size_t)(w * 64 + 16 + col) * K + qq * 8;
    const short* wp2 = Wt + (size_t)(w * 64 + 32 + col) * K + qq * 8;
    const short* wp3 = Wt + (size_t)(w * 64 + 48 + col) * K + qq * 8;
    // LDS byte bases (generic shared addr: low 32 bits are the LDS offset);
    // abH covers sample rows >= 128 (imm field is 16-bit).
    const unsigned ab  = (unsigned)(size_t)(const void*)A + (unsigned)((col * HS + qq * 8) * 2);
    const unsigned abH = ab + 8 * 16 * HS * 2;

    short8 wa[2][4], ba[2][4];   // wa: kstep ping-pong; ba: phase ping-pong

    GLB_LOAD(wa[0][0], wp0, 0);
    GLB_LOAD(wa[0][1], wp1, 0);
    GLB_LOAD(wa[0][2], wp2, 0);
    GLB_LOAD(wa[0][3], wp3, 0);
    LDS_READ(ba[0][0], ab, (0 * 16 * HS) * 2);   // A(P=0): rows 0..3
    LDS_READ(ba[0][1], ab, (1 * 16 * HS) * 2);
    LDS_READ(ba[0][2], ab, (2 * 16 * HS) * 2);
    LDS_READ(ba[0][3], ab, (3 * 16 * HS) * 2);

    f32x4 acc[4][16];   // [ft][st] -- const-indexed after unroll (AGPRs)
#pragma unroll
    for (int ft = 0; ft < 4; ft++)
#pragma unroll
        for (int st = 0; st < 16; st++) acc[ft][st] = (f32x4)0.0f;

#pragma unroll
    for (int P = 0; P < NPH; P++) {
        const int kk = P >> 2, q = P & 3, ca = P & 1, cw = kk & 1;
        if (q == 0 && kk + 1 < KSTEPS) {
            GLB_LOAD(wa[cw ^ 1][0], wp0, (kk + 1) * 64);
            GLB_LOAD(wa[cw ^ 1][1], wp1, (kk + 1) * 64);
            GLB_LOAD(wa[cw ^ 1][2], wp2, (kk + 1) * 64);
            GLB_LOAD(wa[cw ^ 1][3], wp3, (kk + 1) * 64);
        }
        if (P + 1 < NPH) {
            const int nP = P + 1, nkk = nP >> 2, nq = nP & 3, na = nP & 1;
            LDS_READ(ba[na][0], (nq < 2 ? ab : abH), (((nq * 4 + 0) & 7) * 16 * HS) * 2 + nkk * 64);
            LDS_READ(ba[na][1], (nq < 2 ? ab : abH), (((nq * 4 + 1) & 7) * 16 * HS) * 2 + nkk * 64);
            LDS_READ(ba[na][2], (nq < 2 ? ab : abH), (((nq * 4 + 2) & 7) * 16 * HS) * 2 + nkk * 64);
            LDS_READ(ba[na][3], (nq < 2 ? ab : abH), (((nq * 4 + 3) & 7) * 16 * HS) * 2 + nkk * 64);
        }
        if (kk + 1 < KSTEPS) { WAITCNT(4, 4); }                 // W(kk)/A(P) ready
        else if (P + 1 < NPH) { WAITCNT(0, 4); }                // last kstep, mid
        else                  { WAITCNT(0, 0); }                // drain: self-contained
        __builtin_amdgcn_s_setprio(1);
#pragma unroll
        for (int ft = 0; ft < 4; ft++)
#pragma unroll
            for (int st = 0; st < 4; st++)
                acc[ft][q * 4 + st] = __builtin_amdgcn_mfma_f32_16x16x32_bf16(
                    wa[cw][ft], ba[ca][st], acc[ft][q * 4 + st], 0, 0, 0);
        __builtin_amdgcn_s_setprio(0);
    }

    bar_only();   // ALL waves done reading A before ANY epilogue write (A aliases O)

#pragma unroll
    for (int ft = 0; ft < 4; ft++) {
        const f32x4 bv = *(const f32x4*)(bias + w * 64 + ft * 16 + qq * 4);
#pragma unroll
        for (int st = 0; st < 16; st++) {
            float v0 = acc[ft][st][0] + bv[0];
            float v1 = acc[ft][st][1] + bv[1];
            float v2 = acc[ft][st][2] + bv[2];
            float v3 = acc[ft][st][3] + bv[3];
            if (RELU) {
                v0 = fmaxf(v0, 0.0f); v1 = fmaxf(v1, 0.0f);
                v2 = fmaxf(v2, 0.0f); v3 = fmaxf(v3, 0.0f);
            }
            unsigned p0, p1;   // RNE pack, matches f2bf
            asm("v_cvt_pk_bf16_f32 %0, %1, %2" : "=v"(p0) : "v"(v0), "v"(v1));
            asm("v_cvt_pk_bf16_f32 %0, %1, %2" : "=v"(p1) : "v"(v2), "v"(v3));
            uint2v pk; pk[0] = p0; pk[1] = p1;
            *(uint2v*)(O + (size_t)(st * 16 + col) * HS + w * 64 + ft * 16 + qq * 4) = pk;
        }
    }
    bar_lgkm();   // O visible to next layer
}

// head (swapped): four 64-sample groups; wave w handles samples g*64 + w*16 + col.
// Plain C -- our asm queues are empty here (layers drain), compiler waits exact.
template <int NV, int OS>
__device__ __forceinline__ void head256(const short* A, const short* __restrict__ Wt,
                                        const float* __restrict__ bias,
                                        float* Out, int tid)
{
    const int w = tid >> 6, lane = tid & 63, qq = lane >> 4, col = lane & 15;
#pragma unroll
    for (int g = 0; g < 4; g++) {
        const int s = g * 64 + w * 16 + col;
        f32x4 acc = (f32x4)0.0f;
#pragma unroll
        for (int kk = 0; kk < 8; kk++) {
            short8 a = *(const short8*)(Wt + col * 256 + kk * 32 + qq * 8);
            short8 b = *(const short8*)(A + (size_t)s * HS + kk * 32 + qq * 8);
            acc = __builtin_amdgcn_mfma_f32_16x16x32_bf16(a, b, acc, 0, 0, 0);
        }
        if (qq == 0) {
#pragma unroll
            for (int i = 0; i < 4; i++) Out[s * OS + i] = acc[i] + bias[i];
        } else if (NV == 5 && qq == 1) {
            Out[s * OS + 4] = acc[0] + bias[4];
        }
    }
}

__global__ __launch_bounds__(256, 1)
void nerf_mlp(const float* __restrict__ points, const float* __restrict__ dirsv,
              const float* __restrict__ timev, const short* __restrict__ wt,
              const float* __restrict__ sb0, const float* __restrict__ sb1,
              const float* __restrict__ sb2, const float* __restrict__ sb3,
              const float* __restrict__ sb4,
              const float* __restrict__ db0, const float* __restrict__ db1,
              const float* __restrict__ db2, const float* __restrict__ db3,
              const float* __restrict__ db4,
              float* __restrict__ o_sigma, float* __restrict__ o_r,
              float* __restrict__ o_g, float* __restrict__ o_b,
              float* __restrict__ o_bw)
{
    __shared__ __align__(16) short Hb[BM][HS];  // 135168 B (acts; encoding in-place)
    __shared__ float so[BM][4];                 //   4096 B
    __shared__ float dn[BM][5];                 //   5120 B -> 144384 B => 1 block/CU

    const int tid = threadIdx.x;
    const int m0  = blockIdx.x * BM;

    // ---- encoding -> Hb rows[0..127] ----
    encode_E(&Hb[0][0], points, dirsv, timev, m0, tid);
    bar_lgkm();

    // ---- static MLP (L0 reads Hb[.][0..127] in-place) ----
    layer256<4, true>(&Hb[0][0], wt + SW0, sb0, &Hb[0][0], tid);
    layer256<8, true>(&Hb[0][0], wt + SW1, sb1, &Hb[0][0], tid);
    layer256<8, true>(&Hb[0][0], wt + SW2, sb2, &Hb[0][0], tid);
    layer256<8, true>(&Hb[0][0], wt + SW3, sb3, &Hb[0][0], tid);
    head256<4, 4>(&Hb[0][0], wt + SW4, sb4, &so[0][0], tid);
    bar_only();   // heads' Hb reads complete before re-encode overwrites rows[0..127]

    // ---- re-encode (cheap double-angle) + dynamic MLP ----
    encode_E(&Hb[0][0], points, dirsv, timev, m0, tid);
    bar_lgkm();
    layer256<4, true>(&Hb[0][0], wt + DW0, db0, &Hb[0][0], tid);
    layer256<8, true>(&Hb[0][0], wt + DW1, db1, &Hb[0][0], tid);
    layer256<8, true>(&Hb[0][0], wt + DW2, db2, &Hb[0][0], tid);
    layer256<8, true>(&Hb[0][0], wt + DW3, db3, &Hb[0][0], tid);
    head256<5, 5>(&Hb[0][0], wt + DW4, db4, &dn[0][0], tid);
    bar_lgkm();

    // ---- blend (all 256 threads = all samples) ----
    {
        const int s = tid, m = m0 + s;
        const float bw = sigm(dn[s][4]);
        const float sigma = (1.f - bw) * so[s][0] + bw * dn[s][0];
        const float r  = (1.f - bw) * sigm(so[s][1]) + bw * sigm(dn[s][1]);
        const float gg = (1.f - bw) * sigm(so[s][2]) + bw * sigm(dn[s][2]);
        const float bb = (1.f - bw) * sigm(so[s][3]) + bw * sigm(dn[s][3]);
        o_sigma[m] = sigma; o_r[m] = r; o_g[m] = gg; o_b[m] = bb; o_bw[m] = bw;
    }
}

// ---------------- compositing: one wave per ray, float2-vectorized (r12) --------
__global__ __launch_bounds__(256)
void nerf_comp(const float* __restrict__ zv,
               const float* __restrict__ o_sigma, const float* __restrict__ o_r,
               const float* __restrict__ o_g, const float* __restrict__ o_b,
               const float* __restrict__ o_bw, float* __restrict__ out)
{
    const int ray  = blockIdx.x * 4 + (threadIdx.x >> 6);
    const int lane = threadIdx.x & 63;
    const int base = ray * SAMP;

    const f32x2 z01 = *(const f32x2*)(zv + base + 2 * lane);
    const float z0 = z01[0], z1 = z01[1];
    const float z2 = __shfl_down(z0, 1);
    const float d0 = z1 - z0;
    const float d1 = (lane < 63) ? (z2 - z1) : 1e10f;

    const f32x2 sg = *(const f32x2*)(o_sigma + base + 2 * lane);
    const float a0 = 1.0f - expf(-sg[0] * d0);
    const float a1 = 1.0f - expf(-sg[1] * d1);
    const float f0 = 1.0f - a0 + 1e-10f;
    const float f1 = 1.0f - a1 + 1e-10f;

    float incl = f0 * f1;
#pragma unroll
    for (int dlt = 1; dlt < 64; dlt <<= 1) {
        const float t = __shfl_up(incl, dlt);
        if (lane >= dlt) incl *= t;
    }
    float ex = __shfl_up(incl, 1);
    if (lane == 0) ex = 1.0f;

    const float t0 = ex;
    const float t1 = ex * f0;
    const float w0 = a0 * t0, w1 = a1 * t1;

    const f32x2 bw2 = *(const f32x2*)(o_bw + base + 2 * lane);
    f32x2 vw;  vw[0] = w0;                   vw[1] = w1;
    f32x2 vsw; vsw[0] = (1.f - bw2[0]) * w0; vsw[1] = (1.f - bw2[1]) * w1;
    f32x2 vdw; vdw[0] = bw2[0] * w0;         vdw[1] = bw2[1] * w1;
    *(f32x2*)(out + OUT_W  + base + 2 * lane) = vw;
    *(f32x2*)(out + OUT_SW + base + 2 * lane) = vsw;
    *(f32x2*)(out + OUT_DW + base + 2 * lane) = vdw;

    const f32x2 r2 = *(const f32x2*)(o_r + base + 2 * lane);
    const f32x2 g2 = *(const f32x2*)(o_g + base + 2 * lane);
    const f32x2 b2 = *(const f32x2*)(o_b + base + 2 * lane);
    float pr = w0 * r2[0] + w1 * r2[1];
    float pg = w0 * g2[0] + w1 * g2[1];
    float pb = w0 * b2[0] + w1 * b2[1];
    float pd = w0 * z0 + w1 * z1;
#pragma unroll
    for (int dlt = 32; dlt >= 1; dlt >>= 1) {
        pr += __shfl_down(pr, dlt);
        pg += __shfl_down(pg, dlt);
        pb += __shfl_down(pb, dlt);
        pd += __shfl_down(pd, dlt);
    }
    if (lane == 0) {
        out[OUT_RGB + ray * 3 + 0] = pr;
        out[OUT_RGB + ray * 3 + 1] = pg;
        out[OUT_RGB + ray * 3 + 2] = pb;
        out[OUT_DEPTH + ray] = pd;
    }
}

extern "C" void kernel_launch(void* const* d_in, const int* in_sizes, int n_in,
                              void* d_out, int out_size, void* d_ws, size_t ws_size,
                              hipStream_t stream)
{
    const float* points = (const float*)d_in[0];
    const float* dirsv  = (const float*)d_in[1];
    const float* zvals  = (const float*)d_in[2];
    const float* timev  = (const float*)d_in[3];

    const float *sW[5], *sb[5], *dW[5], *db[5];
    if (in_sizes[6] == 99 * 256) {
        for (int i = 0; i < 5; i++) {   // interleaved (sW_i, sb_i, dW_i, db_i)
            sW[i] = (const float*)d_in[4 + 4 * i + 0];
            sb[i] = (const float*)d_in[4 + 4 * i + 1];
            dW[i] = (const float*)d_in[4 + 4 * i + 2];
            db[i] = (const float*)d_in[4 + 4 * i + 3];
        }
    } else {
        for (int i = 0; i < 5; i++) {   // all static then all dynamic
            sW[i] = (const float*)d_in[4 + 2 * i + 0];
            sb[i] = (const float*)d_in[4 + 2 * i + 1];
            dW[i] = (const float*)d_in[14 + 2 * i + 0];
            db[i] = (const float*)d_in[14 + 2 * i + 1];
        }
    }

    // ws layout: bf16 weights (933888 B) then 5 fp32 per-sample arrays (1 MB each)
    short* wt = (short*)d_ws;
    float* ws = (float*)((char*)d_ws + (size_t)WTOT * 2);
    float* o_sigma = ws;
    float* o_r  = ws + (size_t)MTOT * 1;
    float* o_g  = ws + (size_t)MTOT * 2;
    float* o_b  = ws + (size_t)MTOT * 3;
    float* o_bw = ws + (size_t)MTOT * 4;

    prep_weights<<<(WTOT + 255) / 256, 256, 0, stream>>>(
        sW[0], sW[1], sW[2], sW[3], sW[4], dW[0], dW[1], dW[2], dW[3], dW[4], wt);

    nerf_mlp<<<MTOT / BM, 256, 0, stream>>>(points, dirsv, timev, wt,
        sb[0], sb[1], sb[2], sb[3], sb[4], db[0], db[1], db[2], db[3], db[4],
        o_sigma, o_r, o_g, o_b, o_bw);

    nerf_comp<<<RAYS / 4, 256, 0, stream>>>(zvals, o_sigma, o_r, o_g, o_b, o_bw,
                                            (float*)d_out);
}

// Round 17
// 385.718 us; speedup vs baseline: 1.7799x; 1.7799x over previous
//
#include <hip/hip_runtime.h>
#include <math.h>

// FusionNeRF round 19 (= r18 with the spill fixed):
//   - r18 post-mortem: logic passed but noinline layer256 was compiled against
//     the DEFAULT ABI register budget, not the kernel's launch_bounds(256,1)
//     512-reg budget -> 256-AGPR acc spilled to scratch (FETCH 923MB, WRITE
//     1.8GB, 2.7MB/block). The BM=256 theory was never actually measured.
//   - r19: fully inline layer256/encode_E so the allocator sees the 1-wave/SIMD
//     budget (~330 of 512 regs needed). Everything else identical to r18:
//     BM=256, in-place encoding into Hb (BAR1 alias protocol), re-encode before
//     dynamic MLP, 4-quarter counted-wait k-step (validated correct by r18's
//     passing run).

#define RAYS 2048
#define SAMP 128
#define MTOT (RAYS * SAMP)
#define HD   256
#define BM   256             // samples per block
#define HS   264             // act LDS stride (bf16), 256 (+8 pad)

// output float offsets
#define OUT_RGB   0
#define OUT_DEPTH 6144
#define OUT_W     8192
#define OUT_SW    270336
#define OUT_DW    532480

// bf16 weight workspace offsets (elements)
#define SW0 0
#define SW1 32768
#define SW2 98304
#define SW3 163840
#define SW4 229376
#define DW0 233472
#define DW1 266240
#define DW2 331776
#define DW3 397312
#define DW4 462848
#define WTOT 466944

typedef __attribute__((ext_vector_type(8))) short short8;
typedef __attribute__((ext_vector_type(4))) float f32x4;
typedef __attribute__((ext_vector_type(2))) float f32x2;
typedef __attribute__((ext_vector_type(2))) unsigned int uint2v;

__device__ __forceinline__ float sigm(float x) { return 1.0f / (1.0f + expf(-x)); }

__device__ __forceinline__ short f2bf(float f) {   // RNE fp32 -> bf16
    union { float f; unsigned u; } v; v.f = f;
    unsigned r = v.u + 0x7fffu + ((v.u >> 16) & 1u);
    return (short)(r >> 16);
}

// Unmovable memory ops (volatile asm). Counted waits + sched_barrier(0) (rule #18).
#define GLB_LOAD(dst, ptr, imm) \
    asm volatile("global_load_dwordx4 %0, %1, off offset:%c2" \
                 : "=v"(dst) : "v"(ptr), "n"(imm))
#define LDS_READ(dst, addr, imm) \
    asm volatile("ds_read_b128 %0, %1 offset:%c2" \
                 : "=v"(dst) : "v"(addr), "n"(imm))
#define WAITCNT(vm, lg) do { \
    asm volatile("s_waitcnt vmcnt(%c0) lgkmcnt(%c1)" :: "n"(vm), "n"(lg)); \
    __builtin_amdgcn_sched_barrier(0); } while (0)

// Barrier with LDS drain only (validated r5/r8/r12/r14/r16).
__device__ __forceinline__ void bar_lgkm() {
    __builtin_amdgcn_sched_barrier(0);
    asm volatile("s_waitcnt lgkmcnt(0)\n\ts_barrier" ::: "memory");
    __builtin_amdgcn_sched_barrier(0);
}
// Ordering-only barrier (all reads already drained / consumed by dataflow).
__device__ __forceinline__ void bar_only() {
    __builtin_amdgcn_sched_barrier(0);
    asm volatile("s_barrier" ::: "memory");
    __builtin_amdgcn_sched_barrier(0);
}

// ---------------- weight prep: W[K][N] fp32 -> Wt[Npad][Kpad] bf16 --------------
__device__ __forceinline__ void conv1(const float* __restrict__ src, short* __restrict__ dst,
                                      int local, int K, int N, int Kpad) {
    const int n = local / Kpad, k = local - n * Kpad;
    const float v = (k < K && n < N) ? src[k * N + n] : 0.0f;
    dst[local] = f2bf(v);
}

__global__ __launch_bounds__(256)
void prep_weights(const float* sW0, const float* sW1, const float* sW2,
                  const float* sW3, const float* sW4,
                  const float* dW0, const float* dW1, const float* dW2,
                  const float* dW3, const float* dW4, short* __restrict__ dst)
{
    const int idx = blockIdx.x * 256 + threadIdx.x;
    if (idx >= WTOT) return;
    if      (idx < SW1) conv1(sW0, dst + SW0, idx - SW0,  90, 256, 128);
    else if (idx < SW2) conv1(sW1, dst + SW1, idx - SW1, 256, 256, 256);
    else if (idx < SW3) conv1(sW2, dst + SW2, idx - SW2, 256, 256, 256);
    else if (idx < SW4) conv1(sW3, dst + SW3, idx - SW3, 256, 256, 256);
    else if (idx < DW0) conv1(sW4, dst + SW4, idx - SW4, 256,   4, 256);
    else if (idx < DW1) conv1(dW0, dst + DW0, idx - DW0,  99, 256, 128);
    else if (idx < DW2) conv1(dW1, dst + DW1, idx - DW1, 256, 256, 256);
    else if (idx < DW3) conv1(dW2, dst + DW2, idx - DW2, 256, 256, 256);
    else if (idx < DW4) conv1(dW3, dst + DW3, idx - DW3, 256, 256, 256);
    else                conv1(dW4, dst + DW4, idx - DW4, 256,   5, 256);
}

// ---------------- encoding -> Hb rows[0..255] k[0..127] (stride HS) -------------
__device__ __forceinline__
void encode_E(short* __restrict__ Hb, const float* __restrict__ points,
              const float* __restrict__ dirsv, const float* __restrict__ timev,
              int m0, int tid)
{
    for (int idx = tid; idx < 7 * BM; idx += 256) {
        const int c = idx >> 8, s = idx & 255, m = m0 + s;   // c wave-uniform
        short* E = Hb + (size_t)s * HS;
        float x; int dbase, nb, dstep, coff;
        if (c < 3)      { x = points[m * 3 + c];     E[c]      = f2bf(x); dbase = 3 + c;  nb = 10; dstep = 6; coff = 3; }
        else if (c < 6) { x = dirsv[m * 3 + c - 3];  E[60 + c] = f2bf(x); dbase = 63 + c; nb = 4;  dstep = 6; coff = 3; }
        else            { x = timev[m];              E[90]     = f2bf(x); dbase = 91;     nb = 4;  dstep = 2; coff = 1; }
        float sl = sinf(x), cl = cosf(x);
        int d = dbase;
        E[d] = f2bf(sl); E[d + coff] = f2bf(cl);
        for (int l = 1; l < nb; l++) {
            const float s2 = 2.0f * sl * cl;
            const float c2 = cl * cl - sl * sl;
            d += dstep;
            E[d] = f2bf(s2); E[d + coff] = f2bf(c2);
            sl = s2; cl = c2;
        }
    }
    for (int idx = tid; idx < BM * 32; idx += 256) {   // zero pad k=99..127
        const int s = idx >> 5, d = 96 + (idx & 31);
        if (d >= 99) Hb[(size_t)s * HS + d] = 0;
    }
}

// ---------------- MFMA dense layer: 64feat x 256samp per wave, 4-quarter kstep --
// A-operand = weights Wt[256][K] (global, L2-hot), B-operand = acts [256][HS] (LDS,
// may alias O in-place -- BAR1 protocol). Phases P=0..4*KS-1 (kk=P>>2, q=P&3):
// q0 issues W(kk+1); every phase issues A(P+1). Waits: (4,4) steady, (0,4) last
// kstep, (0,0) final phase -- layer self-contained (nothing crosses plain-C).
template <int KSTEPS, bool RELU>
__device__ __forceinline__
void layer256(const short* A, const short* __restrict__ Wt,
              const float* __restrict__ bias, short* O, int tid)
{
    const int w = tid >> 6, lane = tid & 63, qq = lane >> 4, col = lane & 15;
    constexpr int K = KSTEPS * 32;
    constexpr int NPH = 4 * KSTEPS;

    const short* wp0 = Wt + (size_t)(w * 64 +  0 + col) * K + qq * 8;
    const short* wp1 = Wt + (size_t)(w * 64 + 16 + col) * K + qq * 8;
    const short* wp2 = Wt + (size_t)(w * 64 + 32 + col) * K + qq * 8;
    const short* wp3 = Wt + (size_t)(w * 64 + 48 + col) * K + qq * 8;
    // LDS byte bases (generic shared addr: low 32 bits are the LDS offset);
    // abH covers sample rows >= 128 (imm field is 16-bit).
    const unsigned ab  = (unsigned)(size_t)(const void*)A + (unsigned)((col * HS + qq * 8) * 2);
    const unsigned abH = ab + 8 * 16 * HS * 2;

    short8 wa[2][4], ba[2][4];   // wa: kstep ping-pong; ba: phase ping-pong

    GLB_LOAD(wa[0][0], wp0, 0);
    GLB_LOAD(wa[0][1], wp1, 0);
    GLB_LOAD(wa[0][2], wp2, 0);
    GLB_LOAD(wa[0][3], wp3, 0);
    LDS_READ(ba[0][0], ab, (0 * 16 * HS) * 2);   // A(P=0): rows 0..3
    LDS_READ(ba[0][1], ab, (1 * 16 * HS) * 2);
    LDS_READ(ba[0][2], ab, (2 * 16 * HS) * 2);
    LDS_READ(ba[0][3], ab, (3 * 16 * HS) * 2);

    f32x4 acc[4][16];   // [ft][st] -- const-indexed after unroll (AGPRs)
#pragma unroll
    for (int ft = 0; ft < 4; ft++)
#pragma unroll
        for (int st = 0; st < 16; st++) acc[ft][st] = (f32x4)0.0f;

#pragma unroll
    for (int P = 0; P < NPH; P++) {
        const int kk = P >> 2, q = P & 3, ca = P & 1, cw = kk & 1;
        if (q == 0 && kk + 1 < KSTEPS) {
            GLB_LOAD(wa[cw ^ 1][0], wp0, (kk + 1) * 64);
            GLB_LOAD(wa[cw ^ 1][1], wp1, (kk + 1) * 64);
            GLB_LOAD(wa[cw ^ 1][2], wp2, (kk + 1) * 64);
            GLB_LOAD(wa[cw ^ 1][3], wp3, (kk + 1) * 64);
        }
        if (P + 1 < NPH) {
            const int nP = P + 1, nkk = nP >> 2, nq = nP & 3, na = nP & 1;
            LDS_READ(ba[na][0], (nq < 2 ? ab : abH), (((nq * 4 + 0) & 7) * 16 * HS) * 2 + nkk * 64);
            LDS_READ(ba[na][1], (nq < 2 ? ab : abH), (((nq * 4 + 1) & 7) * 16 * HS) * 2 + nkk * 64);
            LDS_READ(ba[na][2], (nq < 2 ? ab : abH), (((nq * 4 + 2) & 7) * 16 * HS) * 2 + nkk * 64);
            LDS_READ(ba[na][3], (nq < 2 ? ab : abH), (((nq * 4 + 3) & 7) * 16 * HS) * 2 + nkk * 64);
        }
        if (kk + 1 < KSTEPS) { WAITCNT(4, 4); }                 // W(kk)/A(P) ready
        else if (P + 1 < NPH) { WAITCNT(0, 4); }                // last kstep, mid
        else                  { WAITCNT(0, 0); }                // drain: self-contained
        __builtin_amdgcn_s_setprio(1);
#pragma unroll
        for (int ft = 0; ft < 4; ft++)
#pragma unroll
            for (int st = 0; st < 4; st++)
                acc[ft][q * 4 + st] = __builtin_amdgcn_mfma_f32_16x16x32_bf16(
                    wa[cw][ft], ba[ca][st], acc[ft][q * 4 + st], 0, 0, 0);
        __builtin_amdgcn_s_setprio(0);
    }

    bar_only();   // ALL waves done reading A before ANY epilogue write (A aliases O)

#pragma unroll
    for (int ft = 0; ft < 4; ft++) {
        const f32x4 bv = *(const f32x4*)(bias + w * 64 + ft * 16 + qq * 4);
#pragma unroll
        for (int st = 0; st < 16; st++) {
            float v0 = acc[ft][st][0] + bv[0];
            float v1 = acc[ft][st][1] + bv[1];
            float v2 = acc[ft][st][2] + bv[2];
            float v3 = acc[ft][st][3] + bv[3];
            if (RELU) {
                v0 = fmaxf(v0, 0.0f); v1 = fmaxf(v1, 0.0f);
                v2 = fmaxf(v2, 0.0f); v3 = fmaxf(v3, 0.0f);
            }
            unsigned p0, p1;   // RNE pack, matches f2bf
            asm("v_cvt_pk_bf16_f32 %0, %1, %2" : "=v"(p0) : "v"(v0), "v"(v1));
            asm("v_cvt_pk_bf16_f32 %0, %1, %2" : "=v"(p1) : "v"(v2), "v"(v3));
            uint2v pk; pk[0] = p0; pk[1] = p1;
            *(uint2v*)(O + (size_t)(st * 16 + col) * HS + w * 64 + ft * 16 + qq * 4) = pk;
        }
    }
    bar_lgkm();   // O visible to next layer
}

// head (swapped): four 64-sample groups; wave w handles samples g*64 + w*16 + col.
// Plain C -- our asm queues are empty here (layers drain), compiler waits exact.
template <int NV, int OS>
__device__ __forceinline__ void head256(const short* A, const short* __restrict__ Wt,
                                        const float* __restrict__ bias,
                                        float* Out, int tid)
{
    const int w = tid >> 6, lane = tid & 63, qq = lane >> 4, col = lane & 15;
#pragma unroll
    for (int g = 0; g < 4; g++) {
        const int s = g * 64 + w * 16 + col;
        f32x4 acc = (f32x4)0.0f;
#pragma unroll
        for (int kk = 0; kk < 8; kk++) {
            short8 a = *(const short8*)(Wt + col * 256 + kk * 32 + qq * 8);
            short8 b = *(const short8*)(A + (size_t)s * HS + kk * 32 + qq * 8);
            acc = __builtin_amdgcn_mfma_f32_16x16x32_bf16(a, b, acc, 0, 0, 0);
        }
        if (qq == 0) {
#pragma unroll
            for (int i = 0; i < 4; i++) Out[s * OS + i] = acc[i] + bias[i];
        } else if (NV == 5 && qq == 1) {
            Out[s * OS + 4] = acc[0] + bias[4];
        }
    }
}

__global__ __launch_bounds__(256, 1)
void nerf_mlp(const float* __restrict__ points, const float* __restrict__ dirsv,
              const float* __restrict__ timev, const short* __restrict__ wt,
              const float* __restrict__ sb0, const float* __restrict__ sb1,
              const float* __restrict__ sb2, const float* __restrict__ sb3,
              const float* __restrict__ sb4,
              const float* __restrict__ db0, const float* __restrict__ db1,
              const float* __restrict__ db2, const float* __restrict__ db3,
              const float* __restrict__ db4,
              float* __restrict__ o_sigma, float* __restrict__ o_r,
              float* __restrict__ o_g, float* __restrict__ o_b,
              float* __restrict__ o_bw)
{
    __shared__ __align__(16) short Hb[BM][HS];  // 135168 B (acts; encoding in-place)
    __shared__ float so[BM][4];                 //   4096 B
    __shared__ float dn[BM][5];                 //   5120 B -> 144384 B => 1 block/CU

    const int tid = threadIdx.x;
    const int m0  = blockIdx.x * BM;

    // ---- encoding -> Hb (rows 0..255, k 0..127) ----
    encode_E(&Hb[0][0], points, dirsv, timev, m0, tid);
    bar_lgkm();

    // ---- static MLP (L0 reads Hb[.][0..127] in-place) ----
    layer256<4, true>(&Hb[0][0], wt + SW0, sb0, &Hb[0][0], tid);
    layer256<8, true>(&Hb[0][0], wt + SW1, sb1, &Hb[0][0], tid);
    layer256<8, true>(&Hb[0][0], wt + SW2, sb2, &Hb[0][0], tid);
    layer256<8, true>(&Hb[0][0], wt + SW3, sb3, &Hb[0][0], tid);
    head256<4, 4>(&Hb[0][0], wt + SW4, sb4, &so[0][0], tid);
    bar_only();   // heads' Hb reads complete before re-encode overwrites k[0..127]

    // ---- re-encode (cheap double-angle) + dynamic MLP ----
    encode_E(&Hb[0][0], points, dirsv, timev, m0, tid);
    bar_lgkm();
    layer256<4, true>(&Hb[0][0], wt + DW0, db0, &Hb[0][0], tid);
    layer256<8, true>(&Hb[0][0], wt + DW1, db1, &Hb[0][0], tid);
    layer256<8, true>(&Hb[0][0], wt + DW2, db2, &Hb[0][0], tid);
    layer256<8, true>(&Hb[0][0], wt + DW3, db3, &Hb[0][0], tid);
    head256<5, 5>(&Hb[0][0], wt + DW4, db4, &dn[0][0], tid);
    bar_lgkm();

    // ---- blend (all 256 threads = all samples) ----
    {
        const int s = tid, m = m0 + s;
        const float bw = sigm(dn[s][4]);
        const float sigma = (1.f - bw) * so[s][0] + bw * dn[s][0];
        const float r  = (1.f - bw) * sigm(so[s][1]) + bw * sigm(dn[s][1]);
        const float gg = (1.f - bw) * sigm(so[s][2]) + bw * sigm(dn[s][2]);
        const float bb = (1.f - bw) * sigm(so[s][3]) + bw * sigm(dn[s][3]);
        o_sigma[m] = sigma; o_r[m] = r; o_g[m] = gg; o_b[m] = bb; o_bw[m] = bw;
    }
}

// ---------------- compositing: one wave per ray, float2-vectorized (r12) --------
__global__ __launch_bounds__(256)
void nerf_comp(const float* __restrict__ zv,
               const float* __restrict__ o_sigma, const float* __restrict__ o_r,
               const float* __restrict__ o_g, const float* __restrict__ o_b,
               const float* __restrict__ o_bw, float* __restrict__ out)
{
    const int ray  = blockIdx.x * 4 + (threadIdx.x >> 6);
    const int lane = threadIdx.x & 63;
    const int base = ray * SAMP;

    const f32x2 z01 = *(const f32x2*)(zv + base + 2 * lane);
    const float z0 = z01[0], z1 = z01[1];
    const float z2 = __shfl_down(z0, 1);
    const float d0 = z1 - z0;
    const float d1 = (lane < 63) ? (z2 - z1) : 1e10f;

    const f32x2 sg = *(const f32x2*)(o_sigma + base + 2 * lane);
    const float a0 = 1.0f - expf(-sg[0] * d0);
    const float a1 = 1.0f - expf(-sg[1] * d1);
    const float f0 = 1.0f - a0 + 1e-10f;
    const float f1 = 1.0f - a1 + 1e-10f;

    float incl = f0 * f1;
#pragma unroll
    for (int dlt = 1; dlt < 64; dlt <<= 1) {
        const float t = __shfl_up(incl, dlt);
        if (lane >= dlt) incl *= t;
    }
    float ex = __shfl_up(incl, 1);
    if (lane == 0) ex = 1.0f;

    const float t0 = ex;
    const float t1 = ex * f0;
    const float w0 = a0 * t0, w1 = a1 * t1;

    const f32x2 bw2 = *(const f32x2*)(o_bw + base + 2 * lane);
    f32x2 vw;  vw[0] = w0;                   vw[1] = w1;
    f32x2 vsw; vsw[0] = (1.f - bw2[0]) * w0; vsw[1] = (1.f - bw2[1]) * w1;
    f32x2 vdw; vdw[0] = bw2[0] * w0;         vdw[1] = bw2[1] * w1;
    *(f32x2*)(out + OUT_W  + base + 2 * lane) = vw;
    *(f32x2*)(out + OUT_SW + base + 2 * lane) = vsw;
    *(f32x2*)(out + OUT_DW + base + 2 * lane) = vdw;

    const f32x2 r2 = *(const f32x2*)(o_r + base + 2 * lane);
    const f32x2 g2 = *(const f32x2*)(o_g + base + 2 * lane);
    const f32x2 b2 = *(const f32x2*)(o_b + base + 2 * lane);
    float pr = w0 * r2[0] + w1 * r2[1];
    float pg = w0 * g2[0] + w1 * g2[1];
    float pb = w0 * b2[0] + w1 * b2[1];
    float pd = w0 * z0 + w1 * z1;
#pragma unroll
    for (int dlt = 32; dlt >= 1; dlt >>= 1) {
        pr += __shfl_down(pr, dlt);
        pg += __shfl_down(pg, dlt);
        pb += __shfl_down(pb, dlt);
        pd += __shfl_down(pd, dlt);
    }
    if (lane == 0) {
        out[OUT_RGB + ray * 3 + 0] = pr;
        out[OUT_RGB + ray * 3 + 1] = pg;
        out[OUT_RGB + ray * 3 + 2] = pb;
        out[OUT_DEPTH + ray] = pd;
    }
}

extern "C" void kernel_launch(void* const* d_in, const int* in_sizes, int n_in,
                              void* d_out, int out_size, void* d_ws, size_t ws_size,
                              hipStream_t stream)
{
    const float* points = (const float*)d_in[0];
    const float* dirsv  = (const float*)d_in[1];
    const float* zvals  = (const float*)d_in[2];
    const float* timev  = (const float*)d_in[3];

    const float *sW[5], *sb[5], *dW[5], *db[5];
    if (in_sizes[6] == 99 * 256) {
        for (int i = 0; i < 5; i++) {   // interleaved (sW_i, sb_i, dW_i, db_i)
            sW[i] = (const float*)d_in[4 + 4 * i + 0];
            sb[i] = (const float*)d_in[4 + 4 * i + 1];
            dW[i] = (const float*)d_in[4 + 4 * i + 2];
            db[i] = (const float*)d_in[4 + 4 * i + 3];
        }
    } else {
        for (int i = 0; i < 5; i++) {   // all static then all dynamic
            sW[i] = (const float*)d_in[4 + 2 * i + 0];
            sb[i] = (const float*)d_in[4 + 2 * i + 1];
            dW[i] = (const float*)d_in[14 + 2 * i + 0];
            db[i] = (const float*)d_in[14 + 2 * i + 1];
        }
    }

    // ws layout: bf16 weights (933888 B) then 5 fp32 per-sample arrays (1 MB each)
    short* wt = (short*)d_ws;
    float* ws = (float*)((char*)d_ws + (size_t)WTOT * 2);
    float* o_sigma = ws;
    float* o_r  = ws + (size_t)MTOT * 1;
    float* o_g  = ws + (size_t)MTOT * 2;
    float* o_b  = ws + (size_t)MTOT * 3;
    float* o_bw = ws + (size_t)MTOT * 4;

    prep_weights<<<(WTOT + 255) / 256, 256, 0, stream>>>(
        sW[0], sW[1], sW[2], sW[3], sW[4], dW[0], dW[1], dW[2], dW[3], dW[4], wt);

    nerf_mlp<<<MTOT / BM, 256, 0, stream>>>(points, dirsv, timev, wt,
        sb[0], sb[1], sb[2], sb[3], sb[4], db[0], db[1], db[2], db[3], db[4],
        o_sigma, o_r, o_g, o_b, o_bw);

    nerf_comp<<<RAYS / 4, 256, 0, stream>>>(zvals, o_sigma, o_r, o_g, o_b, o_bw,
                                            (float*)d_out);
}